// Round 12
// baseline (195.238 us; speedup 1.0000x reference)
//
#include <hip/hip_runtime.h>

// ---------- types ----------
typedef __attribute__((ext_vector_type(4))) float  f32x4;
typedef __attribute__((ext_vector_type(8))) short  s16x8;   // 8 bf16 (4 VGPRs)
typedef __attribute__((ext_vector_type(8))) unsigned short u16x8;
typedef __attribute__((ext_vector_type(4))) unsigned short u16x4;
typedef __attribute__((ext_vector_type(4))) unsigned int   u32x4;

static __device__ __forceinline__ unsigned short f2bf(float f) {
    unsigned int u = __builtin_bit_cast(unsigned int, f);
    u += 0x7fffu + ((u >> 16) & 1u);      // round-to-nearest-even
    return (unsigned short)(u >> 16);
}

static __device__ __forceinline__ unsigned int cvt_pk_bf16(float lo, float hi) {
    unsigned int r;
    asm("v_cvt_pk_bf16_f32 %0, %1, %2" : "=v"(r) : "v"(lo), "v"(hi));
    return r;
}

static __device__ __forceinline__ void gload16(const void* g, void* l) {
    __builtin_amdgcn_global_load_lds(
        (const __attribute__((address_space(1))) void*)g,
        (__attribute__((address_space(3))) void*)l, 16, 0, 0);
}

// =====================================================================
// Weights-only fp32 -> bf16 convert: Wq,Wk,Wv,Wo -> wb. 2048 blocks.
// =====================================================================
__global__ __launch_bounds__(256)
void convW_kernel(const float* __restrict__ wq, const float* __restrict__ wk,
                  const float* __restrict__ wv, const float* __restrict__ wo,
                  unsigned short* __restrict__ wb)
{
    const int wseg = blockIdx.x >> 9;
    const float* src = wseg == 0 ? wq : wseg == 1 ? wk : wseg == 2 ? wv : wo;
    unsigned short* dst = wb + (size_t)wseg * 1048576;
    const size_t e0 = (size_t)(blockIdx.x & 511) * 2048 + threadIdx.x * 8;
    f32x4 a = *(const f32x4*)(src + e0);
    f32x4 b = *(const f32x4*)(src + e0 + 4);
    u16x8 o;
    #pragma unroll
    for (int i = 0; i < 4; ++i) { o[i] = f2bf(a[i]); o[i + 4] = f2bf(b[i]); }
    *(u16x8*)(dst + e0) = o;
}

// =====================================================================
// QKV GEMM (R10 structure): 256x128 tile, BK=64, 8 waves (4M x 2N),
// dbuf swizzled LDS 96 KB, T14 stage-ahead.
// A = q/k/v fp32 reg-staged + cvt_pk + swizzled ds_write.
// B: BSRC=0 -> bf16 wb via global_load_lds (pre-swizzled source);
//    BSRC=1 -> fp32 reg-staged (fallback = R10 exact).
// grid 768, XCD-swizzled. seg0->Qh*0.125 ; seg1->Kh ; seg2->Vt.
// =====================================================================
template<int BSRC>
__global__ __launch_bounds__(512)
void gemmQKV(const float* __restrict__ A0f, const float* __restrict__ A1f,
             const float* __restrict__ A2f,
             const float* __restrict__ B0f, const float* __restrict__ B1f,
             const float* __restrict__ B2f, const unsigned short* __restrict__ Bb16,
             unsigned short* __restrict__ O0, unsigned short* __restrict__ O1,
             unsigned short* __restrict__ O2)
{
    __shared__ unsigned short Asw[2][256 * 64];   // 64 KB
    __shared__ unsigned short Bsw[2][128 * 64];   // 32 KB

    const int tid  = threadIdx.x;
    const int lane = tid & 63;
    const int wave = tid >> 6;
    const int wr   = wave >> 1, wc = wave & 1;    // 4M x 2N waves, 64x64 each
    const int g    = lane >> 4, l16 = lane & 15;

    const int wg   = (blockIdx.x & 7) * 96 + (blockIdx.x >> 3);  // bijective XCD swizzle
    const int bx   = wg & 7;
    const int byt  = wg >> 3;
    const int seg  = byt >> 5;
    const int byl  = byt & 31;

    const float* Af = seg == 0 ? A0f : seg == 1 ? A1f : A2f;
    const float* Arowf = Af + (size_t)(byl * 256) * 1024;
    const float* Browf = (seg == 0 ? B0f : seg == 1 ? B1f : B2f)
                       + (size_t)(bx * 128) * 1024;
    const unsigned short* Browb = Bb16 + (size_t)seg * 1048576
                                + (size_t)(bx * 128) * 1024;

    f32x4 acc[4][4] = {};
    f32x4 alo[4], ahi[4];
    f32x4 blo[2], bhi[2];

    auto loadAf = [&](int kt2) {
        #pragma unroll
        for (int j = 0; j < 4; ++j) {
            const float* p = Arowf + (size_t)((j * 512 + tid) >> 3) * 1024
                           + kt2 * 64 + (tid & 7) * 8;
            alo[j] = *(const f32x4*)p;
            ahi[j] = *(const f32x4*)(p + 4);
        }
    };
    auto writeA = [&](int buf) {
        #pragma unroll
        for (int j = 0; j < 4; ++j) {
            const int r = (j * 512 + tid) >> 3, c = tid & 7;
            u32x4 w;
            w[0] = cvt_pk_bf16(alo[j][0], alo[j][1]);
            w[1] = cvt_pk_bf16(alo[j][2], alo[j][3]);
            w[2] = cvt_pk_bf16(ahi[j][0], ahi[j][1]);
            w[3] = cvt_pk_bf16(ahi[j][2], ahi[j][3]);
            *(u32x4*)((char*)Asw[buf] + ((r * 128 + c * 16) ^ ((r & 7) << 4))) = w;
        }
    };
    auto loadBf = [&](int kt2) {
        #pragma unroll
        for (int j = 0; j < 2; ++j) {
            const float* p = Browf + (size_t)((j * 512 + tid) >> 3) * 1024
                           + kt2 * 64 + (tid & 7) * 8;
            blo[j] = *(const f32x4*)p;
            bhi[j] = *(const f32x4*)(p + 4);
        }
    };
    auto writeB = [&](int buf) {
        #pragma unroll
        for (int j = 0; j < 2; ++j) {
            const int r = (j * 512 + tid) >> 3, c = tid & 7;
            u32x4 w;
            w[0] = cvt_pk_bf16(blo[j][0], blo[j][1]);
            w[1] = cvt_pk_bf16(blo[j][2], blo[j][3]);
            w[2] = cvt_pk_bf16(bhi[j][0], bhi[j][1]);
            w[3] = cvt_pk_bf16(bhi[j][2], bhi[j][3]);
            *(u32x4*)((char*)Bsw[buf] + ((r * 128 + c * 16) ^ ((r & 7) << 4))) = w;
        }
    };
    // B bf16 direct-to-LDS: linear dest + inverse-swizzled global source
    auto gloadB = [&](int buf, int kt2) {
        #pragma unroll
        for (int j = 0; j < 2; ++j) {
            const int r  = (j * 512 + tid) >> 3;
            const int cl = (tid & 7) ^ (r & 7);
            gload16(Browb + (size_t)r * 1024 + kt2 * 64 + cl * 8,
                    (char*)Bsw[buf] + j * 8192 + wave * 1024);
        }
    };
    auto lda = [&](const char* Ab, int mi, int ks) -> s16x8 {
        const int row = wr * 64 + mi * 16 + l16;
        const int off = (row * 128 + g * 16 + ks * 64) ^ ((row & 7) << 4);
        return __builtin_bit_cast(s16x8, *(const u16x8*)(Ab + off));
    };
    auto ldb = [&](const char* Bb, int ni, int ks) -> s16x8 {
        const int row = wc * 64 + ni * 16 + l16;
        const int off = (row * 128 + g * 16 + ks * 64) ^ ((row & 7) << 4);
        return __builtin_bit_cast(s16x8, *(const u16x8*)(Bb + off));
    };

    // ---- prologue: stage tile 0 into buf 0 ----
    loadAf(0);
    if (BSRC == 0) gloadB(0, 0); else loadBf(0);
    writeA(0);
    if (BSRC == 1) writeB(0);
    __syncthreads();

    int cur = 0;
    for (int t = 0; t < 16; ++t) {
        const bool hn = (t + 1 < 16);
        if (hn) {                       // issue next-tile global loads EARLY
            loadAf(t + 1);
            if (BSRC == 0) gloadB(cur ^ 1, t + 1); else loadBf(t + 1);
        }

        const char* Ab = (const char*)Asw[cur];
        const char* Bb = (const char*)Bsw[cur];
        #pragma unroll
        for (int ks = 0; ks < 2; ++ks) {
            s16x8 af[4], bf[4];
            #pragma unroll
            for (int mi = 0; mi < 4; ++mi) af[mi] = lda(Ab, mi, ks);
            #pragma unroll
            for (int ni = 0; ni < 4; ++ni) bf[ni] = ldb(Bb, ni, ks);
            __builtin_amdgcn_s_setprio(1);
            #pragma unroll
            for (int mi = 0; mi < 4; ++mi)
                #pragma unroll
                for (int ni = 0; ni < 4; ++ni)
                    acc[mi][ni] = __builtin_amdgcn_mfma_f32_16x16x32_bf16(
                        af[mi], bf[ni], acc[mi][ni], 0, 0, 0);
            __builtin_amdgcn_s_setprio(0);
        }

        if (hn) {                       // convert + write next A tile
            writeA(cur ^ 1);
            if (BSRC == 1) writeB(cur ^ 1);
        }
        __syncthreads();                // drains lgkm + vmcnt before next reads
        cur ^= 1;
    }

    // ---- epilogue ----
    #pragma unroll
    for (int mi = 0; mi < 4; ++mi) {
        #pragma unroll
        for (int ni = 0; ni < 4; ++ni) {
            const int gr0 = byl * 256 + wr * 64 + mi * 16 + g * 4;      // M base
            const int gc  = bx * 128 + wc * 64 + ni * 16 + l16;         // N
            if (seg == 2) {
                // Vt [B,H,64,L]: pack 4 consecutive ll into one 8B store
                const int b = gr0 >> 11, ll = gr0 & 2047;
                const int h = gc >> 6,  dh = gc & 63;
                u16x4 pk;
                #pragma unroll
                for (int rr = 0; rr < 4; ++rr) pk[rr] = f2bf(acc[mi][ni][rr]);
                *(u16x4*)(O2 + (size_t)((b * 16 + h) * 64 + dh) * 2048 + ll) = pk;
            } else {
                #pragma unroll
                for (int rr = 0; rr < 4; ++rr) {
                    const int gr = gr0 + rr;
                    float v = acc[mi][ni][rr];
                    const int b = gr >> 11, ll = gr & 2047;
                    const int h = gc >> 6,  dh = gc & 63;
                    if (seg == 0) {
                        v *= 0.125f;
                        O0[(size_t)((b * 16 + h) * 2048 + ll) * 64 + dh] = f2bf(v);
                    } else {
                        O1[(size_t)((b * 16 + h) * 2048 + ll) * 64 + dh] = f2bf(v);
                    }
                }
            }
        }
    }
}

// =====================================================================
// Out-proj GEMM (R6 ring-3 structure, both operands bf16):
// 256x128 tile, BK=64, 8 waves, ring-3 LDS (144 KB), counted vmcnt(6).
// A = Ctx bf16, B = Wo bf16 (wb+3MB). grid 256. Of fp32 [8192,1024].
// =====================================================================
__global__ __launch_bounds__(512)
void gemmOut(const unsigned short* __restrict__ A0,
             const unsigned short* __restrict__ Bw,
             float* __restrict__ Of)
{
    __shared__ unsigned short Asw[3][256 * 64];   // 96 KB
    __shared__ unsigned short Bsw[3][128 * 64];   // 48 KB

    const int tid  = threadIdx.x;
    const int lane = tid & 63;
    const int wave = tid >> 6;
    const int wr   = wave >> 1, wc = wave & 1;
    const int g    = lane >> 4, l16 = lane & 15;

    const int wg   = (blockIdx.x & 7) * 32 + (blockIdx.x >> 3);
    const int bx   = wg & 7;
    const int byl  = wg >> 3;

    const unsigned short* Arow = A0 + (size_t)(byl * 256) * 1024;
    const unsigned short* Brow = Bw + (size_t)(bx * 128) * 1024;

    f32x4 acc[4][4] = {};

    auto stage = [&](int buf, int kt) {
        #pragma unroll
        for (int j = 0; j < 4; ++j) {
            const int r  = (j * 512 + tid) >> 3;
            const int cl = (tid & 7) ^ (r & 7);
            gload16(Arow + (size_t)r * 1024 + kt * 64 + cl * 8,
                    (char*)Asw[buf] + j * 8192 + wave * 1024);
        }
        #pragma unroll
        for (int j = 0; j < 2; ++j) {
            const int r  = (j * 512 + tid) >> 3;
            const int cl = (tid & 7) ^ (r & 7);
            gload16(Brow + (size_t)r * 1024 + kt * 64 + cl * 8,
                    (char*)Bsw[buf] + j * 8192 + wave * 1024);
        }
    };

    stage(0, 0);
    stage(1, 1);
    asm volatile("s_waitcnt vmcnt(6)" ::: "memory");
    __builtin_amdgcn_s_barrier();

    for (int kt = 0; kt < 16; ++kt) {
        if (kt + 2 < 16) stage((kt + 2) % 3, kt + 2);

        const char* Ab = (const char*)Asw[kt % 3];
        const char* Bb = (const char*)Bsw[kt % 3];
        #pragma unroll
        for (int ks = 0; ks < 2; ++ks) {
            s16x8 af[4], bf[4];
            #pragma unroll
            for (int mi = 0; mi < 4; ++mi) {
                const int row = wr * 64 + mi * 16 + l16;
                const int off = (row * 128 + g * 16 + ks * 64) ^ ((row & 7) << 4);
                af[mi] = __builtin_bit_cast(s16x8, *(const u16x8*)(Ab + off));
            }
            #pragma unroll
            for (int ni = 0; ni < 4; ++ni) {
                const int row = wc * 64 + ni * 16 + l16;
                const int off = (row * 128 + g * 16 + ks * 64) ^ ((row & 7) << 4);
                bf[ni] = __builtin_bit_cast(s16x8, *(const u16x8*)(Bb + off));
            }
            __builtin_amdgcn_s_setprio(1);
            #pragma unroll
            for (int mi = 0; mi < 4; ++mi)
                #pragma unroll
                for (int ni = 0; ni < 4; ++ni)
                    acc[mi][ni] = __builtin_amdgcn_mfma_f32_16x16x32_bf16(
                        af[mi], bf[ni], acc[mi][ni], 0, 0, 0);
            __builtin_amdgcn_s_setprio(0);
        }

        if (kt + 2 < 16) asm volatile("s_waitcnt vmcnt(6)" ::: "memory");
        else             asm volatile("s_waitcnt vmcnt(0)" ::: "memory");
        __builtin_amdgcn_s_barrier();
    }

    #pragma unroll
    for (int mi = 0; mi < 4; ++mi) {
        #pragma unroll
        for (int ni = 0; ni < 4; ++ni) {
            const int gr0 = byl * 256 + wr * 64 + mi * 16 + g * 4;
            const int gc  = bx * 128 + wc * 64 + ni * 16 + l16;
            #pragma unroll
            for (int rr = 0; rr < 4; ++rr)
                Of[(size_t)(gr0 + rr) * 1024 + gc] = acc[mi][ni][rr];
        }
    }
}

// =====================================================================
// Flash-style causal attention, double-buffered KV via global_load_lds
// (pre-swizzled source). Swapped QK^T, per-lane row softmax, defer-max,
// cvt_pk P->bf16.
// =====================================================================
__global__ __launch_bounds__(512)
void attn_kernel(const unsigned short* __restrict__ Qh,
                 const unsigned short* __restrict__ Kh,
                 const unsigned short* __restrict__ Vt,
                 unsigned short* __restrict__ Ctx)
{
    __shared__ unsigned short Ksw[2][64 * 64];
    __shared__ unsigned short Vsw[2][64 * 64];
    __shared__ unsigned short Psw[8][16 * 64];

    const int tid  = threadIdx.x;
    const int lane = tid & 63;
    const int wave = tid >> 6;
    const int g    = lane >> 4, l16 = lane & 15;
    const int qb   = 15 - (int)(blockIdx.x >> 6);
    const int bh   = blockIdx.x & 63;
    const int b    = bh >> 4, h = bh & 15;
    const int qrow0 = qb * 128 + wave * 16;
    const int ntile = 2 * qb + 2;

    // staging: 512 thr x 16B = one 64x64 bf16 tile; row sr, inv-swz chunk cl
    const int sr = tid >> 3;
    const int cl = (tid & 7) ^ (sr & 7);
    const unsigned short* ksrc = Kh + ((size_t)bh * 2048 + sr) * 64 + cl * 8;
    const unsigned short* vsrc = Vt + ((size_t)bh * 64 + sr) * 2048 + cl * 8;

    auto stageKV = [&](int buf, int kv0) {
        gload16(ksrc + (size_t)kv0 * 64, (char*)Ksw[buf] + wave * 1024);
        gload16(vsrc + kv0,              (char*)Vsw[buf] + wave * 1024);
    };

    s16x8 qf[2];
    {
        const unsigned short* qp = Qh + ((size_t)bh * 2048 + qrow0 + l16) * 64 + g * 8;
        qf[0] = __builtin_bit_cast(s16x8, *(const u16x8*)qp);
        qf[1] = __builtin_bit_cast(s16x8, *(const u16x8*)(qp + 32));
    }

    f32x4 o[4] = {};
    float m = -3.0e38f, l = 0.f;   // per-lane row state: q = l16

    stageKV(0, 0);
    __syncthreads();

    int cur = 0;
    for (int t = 0; t < ntile; ++t) {
        const int kv0 = t * 64;
        const bool hn = (t + 1 < ntile);
        if (hn) stageKV(cur ^ 1, kv0 + 64);   // in flight during compute

        if (kv0 <= qrow0 + 15) {
            const char* Kb = (const char*)Ksw[cur];
            const char* Vb = (const char*)Vsw[cur];

            // ---- S^T = K Q^T : st[nt][rr] = S[kv0+nt*16+g*4+rr][qrow0+l16]
            f32x4 st[4] = {};
            __builtin_amdgcn_s_setprio(1);
            #pragma unroll
            for (int nt = 0; nt < 4; ++nt) {
                #pragma unroll
                for (int ks = 0; ks < 2; ++ks) {
                    const int row = nt * 16 + l16;
                    const int off = (row * 128 + g * 16 + ks * 64) ^ ((row & 7) << 4);
                    s16x8 kf = __builtin_bit_cast(s16x8, *(const u16x8*)(Kb + off));
                    st[nt] = __builtin_amdgcn_mfma_f32_16x16x32_bf16(kf, qf[ks], st[nt], 0, 0, 0);
                }
            }
            __builtin_amdgcn_s_setprio(0);

            if (kv0 + 63 > qrow0) {
                const int q_g = qrow0 + l16;
                #pragma unroll
                for (int nt = 0; nt < 4; ++nt)
                    #pragma unroll
                    for (int rr = 0; rr < 4; ++rr) {
                        const int kv_g = kv0 + nt * 16 + g * 4 + rr;
                        if (kv_g > q_g) st[nt][rr] = -3.0e38f;
                    }
            }

            float pmax = fmaxf(
                fmaxf(fmaxf(fmaxf(st[0][0], st[0][1]), fmaxf(st[0][2], st[0][3])),
                      fmaxf(fmaxf(st[1][0], st[1][1]), fmaxf(st[1][2], st[1][3]))),
                fmaxf(fmaxf(fmaxf(st[2][0], st[2][1]), fmaxf(st[2][2], st[2][3])),
                      fmaxf(fmaxf(st[3][0], st[3][1]), fmaxf(st[3][2], st[3][3]))));
            pmax = fmaxf(pmax, __shfl_xor(pmax, 16));
            pmax = fmaxf(pmax, __shfl_xor(pmax, 32));

            if (__all(pmax <= m + 8.0f)) {
                float r0 = 0.f;
                #pragma unroll
                for (int nt = 0; nt < 4; ++nt)
                    #pragma unroll
                    for (int rr = 0; rr < 4; ++rr) {
                        const float p = __expf(st[nt][rr] - m);
                        st[nt][rr] = p;
                        r0 += p;
                    }
                r0 += __shfl_xor(r0, 16);
                r0 += __shfl_xor(r0, 32);
                l += r0;
            } else {
                const float mn = fmaxf(m, pmax);
                const float scf = __expf(m - mn);
                m = mn;
                float r0 = 0.f;
                #pragma unroll
                for (int nt = 0; nt < 4; ++nt)
                    #pragma unroll
                    for (int rr = 0; rr < 4; ++rr) {
                        const float p = __expf(st[nt][rr] - mn);
                        st[nt][rr] = p;
                        r0 += p;
                    }
                r0 += __shfl_xor(r0, 16);
                r0 += __shfl_xor(r0, 32);
                l = l * scf + r0;
                float sc4[4];
                #pragma unroll
                for (int rr = 0; rr < 4; ++rr) sc4[rr] = __shfl(scf, g * 4 + rr);
                #pragma unroll
                for (int nt = 0; nt < 4; ++nt)
                    #pragma unroll
                    for (int rr = 0; rr < 4; ++rr)
                        o[nt][rr] *= sc4[rr];
            }

            unsigned short* Pw = Psw[wave];
            #pragma unroll
            for (int nt = 0; nt < 4; ++nt) {
                const unsigned int w0 = cvt_pk_bf16(st[nt][0], st[nt][1]);
                const unsigned int w1 = cvt_pk_bf16(st[nt][2], st[nt][3]);
                const int off = (l16 * 128 + nt * 32 + g * 8) ^ ((l16 & 7) << 4);
                const unsigned long long dw = ((unsigned long long)w1 << 32) | w0;
                *(unsigned long long*)((char*)Pw + off) = dw;
            }

            __builtin_amdgcn_s_setprio(1);
            #pragma unroll
            for (int ks = 0; ks < 2; ++ks) {
                const int offp = (l16 * 128 + g * 16 + ks * 64) ^ ((l16 & 7) << 4);
                s16x8 pf = __builtin_bit_cast(s16x8, *(const u16x8*)((const char*)Pw + offp));
                #pragma unroll
                for (int nt = 0; nt < 4; ++nt) {
                    const int row = nt * 16 + l16;
                    const int off = (row * 128 + g * 16 + ks * 64) ^ ((row & 7) << 4);
                    s16x8 vf = __builtin_bit_cast(s16x8, *(const u16x8*)(Vb + off));
                    o[nt] = __builtin_amdgcn_mfma_f32_16x16x32_bf16(pf, vf, o[nt], 0, 0, 0);
                }
            }
            __builtin_amdgcn_s_setprio(0);
        }

        __syncthreads();   // drains gload_lds (vmcnt) + lgkm; buf cur^1 ready
        cur ^= 1;
    }

    #pragma unroll
    for (int rr = 0; rr < 4; ++rr) {
        const float lq = __shfl(l, g * 4 + rr);
        const float inv = 1.0f / lq;
        const int q_g = qrow0 + g * 4 + rr;
        #pragma unroll
        for (int nt = 0; nt < 4; ++nt) {
            const int d = nt * 16 + l16;
            Ctx[((size_t)b * 2048 + q_g) * 1024 + h * 64 + d] = f2bf(o[nt][rr] * inv);
        }
    }
}

// =====================================================================
extern "C" void kernel_launch(void* const* d_in, const int* in_sizes, int n_in,
                              void* d_out, int out_size, void* d_ws, size_t ws_size,
                              hipStream_t stream)
{
    const float* q  = (const float*)d_in[0];
    const float* k  = (const float*)d_in[1];
    const float* v  = (const float*)d_in[2];
    const float* Wq = (const float*)d_in[4];
    const float* Wk = (const float*)d_in[5];
    const float* Wv = (const float*)d_in[6];
    const float* Wo = (const float*)d_in[7];

    const size_t NE = (size_t)4 * 16 * 2048 * 64;     // 8,388,608 elems / tensor
    const size_t WE = (size_t)1024 * 1024;
    unsigned short* Qh  = (unsigned short*)d_ws;
    unsigned short* Kh  = Qh + NE;
    unsigned short* Vt  = Kh + NE;
    unsigned short* Ctx = Vt + NE;
    unsigned short* wb  = Ctx + NE;                   // +8 MB -> 72 MB total
    float* outp = (float*)d_out;

    if (ws_size >= 4 * NE * 2 + 4 * WE * 2) {
        // main path: weights pre-converted to bf16
        convW_kernel<<<dim3(2048), dim3(256), 0, stream>>>(Wq, Wk, Wv, Wo, wb);
        gemmQKV<0><<<dim3(768), dim3(512), 0, stream>>>(
            q, k, v, nullptr, nullptr, nullptr, wb, Qh, Kh, Vt);
        attn_kernel<<<dim3(1024), dim3(512), 0, stream>>>(Qh, Kh, Vt, Ctx);
        gemmOut<<<dim3(256), dim3(512), 0, stream>>>(Ctx, wb + 3 * WE, outp);
    } else {
        // fallback = R10 exact flow (fp32 B reg-staged; outproj via attn path
        // not needed since ws has always fit, but keep it safe)
        gemmQKV<1><<<dim3(768), dim3(512), 0, stream>>>(
            q, k, v, Wq, Wk, Wv, nullptr, Qh, Kh, Vt);
        attn_kernel<<<dim3(1024), dim3(512), 0, stream>>>(Qh, Kh, Vt, Ctx);
        convW_kernel<<<dim3(2048), dim3(256), 0, stream>>>(Wq, Wk, Wv, Wo,
                                                           (unsigned short*)d_ws);
        gemmOut<<<dim3(256), dim3(512), 0, stream>>>(
            Ctx, (unsigned short*)d_ws + 3 * WE, outp);
    }
}

// Round 13
// 179.067 us; speedup vs baseline: 1.0903x; 1.0903x over previous
//
#include <hip/hip_runtime.h>

// ---------- types ----------
typedef __attribute__((ext_vector_type(4))) float  f32x4;
typedef __attribute__((ext_vector_type(8))) short  s16x8;   // 8 bf16 (4 VGPRs)
typedef __attribute__((ext_vector_type(8))) unsigned short u16x8;
typedef __attribute__((ext_vector_type(4))) unsigned short u16x4;
typedef __attribute__((ext_vector_type(4))) unsigned int   u32x4;

static __device__ __forceinline__ unsigned short f2bf(float f) {
    unsigned int u = __builtin_bit_cast(unsigned int, f);
    u += 0x7fffu + ((u >> 16) & 1u);      // round-to-nearest-even
    return (unsigned short)(u >> 16);
}

static __device__ __forceinline__ unsigned int cvt_pk_bf16(float lo, float hi) {
    unsigned int r;
    asm("v_cvt_pk_bf16_f32 %0, %1, %2" : "=v"(r) : "v"(lo), "v"(hi));
    return r;
}

static __device__ __forceinline__ void gload16(const void* g, void* l) {
    __builtin_amdgcn_global_load_lds(
        (const __attribute__((address_space(1))) void*)g,
        (__attribute__((address_space(3))) void*)l, 16, 0, 0);
}

// =====================================================================
// bf16 NT GEMM with IN-KERNEL fp32->bf16 staging (R10 configuration —
// measured best: total 178.9 us).
// 256x128 tile, BK=64, 8 waves (4M x 2N, 64x64 each), double-buffered
// swizzled LDS (96 KB), T14 stage-ahead:
//   iter t: {issue global loads for t+1 -> regs (or gload_lds for bf16 A)}
//           {ds_read cur + 32 MFMA}
//           {convert + swizzled ds_write t+1 -> buf^1}
//           {__syncthreads}
// EPI 0: A = q/k/v fp32, B = Wq/Wk/Wv fp32. grid 768, XCD-swizzled.
//        seg0 -> Qh [B,H,L,64] * 0.125 ; seg1 -> Kh ; seg2 -> Vt [B,H,64,L]
// EPI 1: A = Ctx bf16 (gload_lds), B = Wo fp32. grid 256. Of fp32.
// =====================================================================
template<int EPI>
__global__ __launch_bounds__(512)
void gemmF(const float* __restrict__ A0f, const float* __restrict__ A1f,
           const float* __restrict__ A2f, const unsigned short* __restrict__ Ab16,
           const float* __restrict__ B0f, const float* __restrict__ B1f,
           const float* __restrict__ B2f,
           unsigned short* __restrict__ O0, unsigned short* __restrict__ O1,
           unsigned short* __restrict__ O2, float* __restrict__ Of)
{
    __shared__ unsigned short Asw[2][256 * 64];   // 64 KB
    __shared__ unsigned short Bsw[2][128 * 64];   // 32 KB

    const int tid  = threadIdx.x;
    const int lane = tid & 63;
    const int wave = tid >> 6;
    const int wr   = wave >> 1, wc = wave & 1;    // 4M x 2N waves, 64x64 each
    const int g    = lane >> 4, l16 = lane & 15;

    const int nblk = (EPI == 0) ? 768 : 256;
    const int cpx  = nblk >> 3;
    const int wg   = (blockIdx.x & 7) * cpx + (blockIdx.x >> 3);  // bijective XCD swizzle
    const int bx   = wg & 7;
    const int byt  = wg >> 3;
    const int seg  = (EPI == 0) ? (byt >> 5) : 0;
    const int byl  = (EPI == 0) ? (byt & 31) : byt;

    const float* Arowf = nullptr;
    const unsigned short* Arowb = nullptr;
    if (EPI == 0) {
        const float* Af = seg == 0 ? A0f : seg == 1 ? A1f : A2f;
        Arowf = Af + (size_t)(byl * 256) * 1024;
    } else {
        Arowb = Ab16 + (size_t)(byl * 256) * 1024;
    }
    const float* Browf = (seg == 0 ? B0f : seg == 1 ? B1f : B2f)
                       + (size_t)(bx * 128) * 1024;

    f32x4 acc[4][4] = {};

    // staging registers for tile t+1 (fp32 path)
    f32x4 alo[4], ahi[4];   // A: 4 chunks x 8 floats (EPI 0 only)
    f32x4 blo[2], bhi[2];   // B: 2 chunks x 8 floats

    // chunk coords: chunk j covers row r=(j*512+tid)>>3, 16B-col c=tid&7
    auto loadAf = [&](int kt2) {
        #pragma unroll
        for (int j = 0; j < 4; ++j) {
            const float* p = Arowf + (size_t)((j * 512 + tid) >> 3) * 1024
                           + kt2 * 64 + (tid & 7) * 8;
            alo[j] = *(const f32x4*)p;
            ahi[j] = *(const f32x4*)(p + 4);
        }
    };
    auto loadBf = [&](int kt2) {
        #pragma unroll
        for (int j = 0; j < 2; ++j) {
            const float* p = Browf + (size_t)((j * 512 + tid) >> 3) * 1024
                           + kt2 * 64 + (tid & 7) * 8;
            blo[j] = *(const f32x4*)p;
            bhi[j] = *(const f32x4*)(p + 4);
        }
    };
    auto writeA = [&](int buf) {
        #pragma unroll
        for (int j = 0; j < 4; ++j) {
            const int r = (j * 512 + tid) >> 3, c = tid & 7;
            u32x4 w;
            w[0] = cvt_pk_bf16(alo[j][0], alo[j][1]);
            w[1] = cvt_pk_bf16(alo[j][2], alo[j][3]);
            w[2] = cvt_pk_bf16(ahi[j][0], ahi[j][1]);
            w[3] = cvt_pk_bf16(ahi[j][2], ahi[j][3]);
            *(u32x4*)((char*)Asw[buf] + ((r * 128 + c * 16) ^ ((r & 7) << 4))) = w;
        }
    };
    auto writeB = [&](int buf) {
        #pragma unroll
        for (int j = 0; j < 2; ++j) {
            const int r = (j * 512 + tid) >> 3, c = tid & 7;
            u32x4 w;
            w[0] = cvt_pk_bf16(blo[j][0], blo[j][1]);
            w[1] = cvt_pk_bf16(blo[j][2], blo[j][3]);
            w[2] = cvt_pk_bf16(bhi[j][0], bhi[j][1]);
            w[3] = cvt_pk_bf16(bhi[j][2], bhi[j][3]);
            *(u32x4*)((char*)Bsw[buf] + ((r * 128 + c * 16) ^ ((r & 7) << 4))) = w;
        }
    };
    // bf16 A staging (EPI 1): direct-to-LDS, linear dest + inv-swizzled source
    auto gloadA = [&](int buf, int kt2) {
        #pragma unroll
        for (int j = 0; j < 4; ++j) {
            const int r  = (j * 512 + tid) >> 3;
            const int cl = (tid & 7) ^ (r & 7);
            gload16(Arowb + (size_t)r * 1024 + kt2 * 64 + cl * 8,
                    (char*)Asw[buf] + j * 8192 + wave * 1024);
        }
    };
    auto lda = [&](const char* Ab, int mi, int ks) -> s16x8 {
        const int row = wr * 64 + mi * 16 + l16;
        const int off = (row * 128 + g * 16 + ks * 64) ^ ((row & 7) << 4);
        return __builtin_bit_cast(s16x8, *(const u16x8*)(Ab + off));
    };
    auto ldb = [&](const char* Bb, int ni, int ks) -> s16x8 {
        const int row = wc * 64 + ni * 16 + l16;
        const int off = (row * 128 + g * 16 + ks * 64) ^ ((row & 7) << 4);
        return __builtin_bit_cast(s16x8, *(const u16x8*)(Bb + off));
    };

    // ---- prologue: stage tile 0 into buf 0 ----
    if (EPI == 0) { loadAf(0); } else { gloadA(0, 0); }
    loadBf(0);
    if (EPI == 0) writeA(0);
    writeB(0);
    __syncthreads();

    int cur = 0;
    for (int t = 0; t < 16; ++t) {
        const bool hn = (t + 1 < 16);
        // issue next-tile global loads EARLY (latency hides under compute)
        if (hn) {
            if (EPI == 0) loadAf(t + 1); else gloadA(cur ^ 1, t + 1);
            loadBf(t + 1);
        }

        const char* Ab = (const char*)Asw[cur];
        const char* Bb = (const char*)Bsw[cur];
        #pragma unroll
        for (int ks = 0; ks < 2; ++ks) {
            s16x8 af[4], bf[4];
            #pragma unroll
            for (int mi = 0; mi < 4; ++mi) af[mi] = lda(Ab, mi, ks);
            #pragma unroll
            for (int ni = 0; ni < 4; ++ni) bf[ni] = ldb(Bb, ni, ks);
            __builtin_amdgcn_s_setprio(1);
            #pragma unroll
            for (int mi = 0; mi < 4; ++mi)
                #pragma unroll
                for (int ni = 0; ni < 4; ++ni)
                    acc[mi][ni] = __builtin_amdgcn_mfma_f32_16x16x32_bf16(
                        af[mi], bf[ni], acc[mi][ni], 0, 0, 0);
            __builtin_amdgcn_s_setprio(0);
        }

        // convert + write next tile into the other buffer
        if (hn) {
            if (EPI == 0) writeA(cur ^ 1);
            writeB(cur ^ 1);
        }
        __syncthreads();   // drains lgkm + vmcnt (gload_lds) before next reads
        cur ^= 1;
    }

    // ---- epilogue ----
    #pragma unroll
    for (int mi = 0; mi < 4; ++mi) {
        #pragma unroll
        for (int ni = 0; ni < 4; ++ni) {
            const int gr0 = byl * 256 + wr * 64 + mi * 16 + g * 4;      // M base
            const int gc  = bx * 128 + wc * 64 + ni * 16 + l16;         // N
            if (EPI == 0 && seg == 2) {
                // Vt [B,H,64,L]: pack 4 consecutive ll into one 8B store
                const int b = gr0 >> 11, ll = gr0 & 2047;
                const int h = gc >> 6,  dh = gc & 63;
                u16x4 pk;
                #pragma unroll
                for (int rr = 0; rr < 4; ++rr) pk[rr] = f2bf(acc[mi][ni][rr]);
                *(u16x4*)(O2 + (size_t)((b * 16 + h) * 64 + dh) * 2048 + ll) = pk;
            } else {
                #pragma unroll
                for (int rr = 0; rr < 4; ++rr) {
                    const int gr = gr0 + rr;
                    float v = acc[mi][ni][rr];
                    if (EPI == 0) {
                        const int b = gr >> 11, ll = gr & 2047;
                        const int h = gc >> 6,  dh = gc & 63;
                        if (seg == 0) {
                            v *= 0.125f;
                            O0[(size_t)((b * 16 + h) * 2048 + ll) * 64 + dh] = f2bf(v);
                        } else {
                            O1[(size_t)((b * 16 + h) * 2048 + ll) * 64 + dh] = f2bf(v);
                        }
                    } else {
                        Of[(size_t)gr * 1024 + gc] = v;
                    }
                }
            }
        }
    }
}

// =====================================================================
// Flash-style causal attention, double-buffered KV (reg-staged).
// Swapped QK^T (S^T = mfma(K,Q)) -> per-lane row softmax (q = l16),
// defer-max (THR=8), cvt_pk P->bf16, b64 P writes.
// =====================================================================
__global__ __launch_bounds__(512)
void attn_kernel(const unsigned short* __restrict__ Qh,
                 const unsigned short* __restrict__ Kh,
                 const unsigned short* __restrict__ Vt,
                 unsigned short* __restrict__ Ctx)
{
    __shared__ unsigned short Ksw[2][64 * 64];
    __shared__ unsigned short Vsw[2][64 * 64];
    __shared__ unsigned short Psw[8][16 * 64];

    const int tid  = threadIdx.x;
    const int lane = tid & 63;
    const int wave = tid >> 6;
    const int g    = lane >> 4, l16 = lane & 15;
    const int qb   = 15 - (int)(blockIdx.x >> 6);
    const int bh   = blockIdx.x & 63;
    const int b    = bh >> 4, h = bh & 15;
    const int qrow0 = qb * 128 + wave * 16;
    const int ntile = 2 * qb + 2;

    const int sr = tid >> 3, sc = tid & 7;
    const int soff = (sr * 128 + sc * 16) ^ ((sr & 7) << 4);
    const unsigned short* kbase = Kh + ((size_t)bh * 2048 + sr) * 64 + sc * 8;
    const unsigned short* vbase = Vt + ((size_t)bh * 64 + sr) * 2048 + sc * 8;

    s16x8 qf[2];
    {
        const unsigned short* qp = Qh + ((size_t)bh * 2048 + qrow0 + l16) * 64 + g * 8;
        qf[0] = __builtin_bit_cast(s16x8, *(const u16x8*)qp);
        qf[1] = __builtin_bit_cast(s16x8, *(const u16x8*)(qp + 32));
    }

    f32x4 o[4] = {};
    float m = -3.0e38f, l = 0.f;   // per-lane row state: q = l16

    *(u16x8*)((char*)Ksw[0] + soff) = *(const u16x8*)kbase;
    *(u16x8*)((char*)Vsw[0] + soff) = *(const u16x8*)vbase;
    __syncthreads();

    int cur = 0;
    for (int t = 0; t < ntile; ++t) {
        const int kv0 = t * 64;

        u16x8 kn, vn;
        const bool hn = (t + 1 < ntile);
        if (hn) {
            kn = *(const u16x8*)(kbase + (size_t)(kv0 + 64) * 64);
            vn = *(const u16x8*)(vbase + (kv0 + 64));
        }

        if (kv0 <= qrow0 + 15) {
            const char* Kb = (const char*)Ksw[cur];
            const char* Vb = (const char*)Vsw[cur];

            f32x4 st[4] = {};
            __builtin_amdgcn_s_setprio(1);
            #pragma unroll
            for (int nt = 0; nt < 4; ++nt) {
                #pragma unroll
                for (int ks = 0; ks < 2; ++ks) {
                    const int row = nt * 16 + l16;
                    const int off = (row * 128 + g * 16 + ks * 64) ^ ((row & 7) << 4);
                    s16x8 kf = __builtin_bit_cast(s16x8, *(const u16x8*)(Kb + off));
                    st[nt] = __builtin_amdgcn_mfma_f32_16x16x32_bf16(kf, qf[ks], st[nt], 0, 0, 0);
                }
            }
            __builtin_amdgcn_s_setprio(0);

            if (kv0 + 63 > qrow0) {
                const int q_g = qrow0 + l16;
                #pragma unroll
                for (int nt = 0; nt < 4; ++nt)
                    #pragma unroll
                    for (int rr = 0; rr < 4; ++rr) {
                        const int kv_g = kv0 + nt * 16 + g * 4 + rr;
                        if (kv_g > q_g) st[nt][rr] = -3.0e38f;
                    }
            }

            float pmax = fmaxf(
                fmaxf(fmaxf(fmaxf(st[0][0], st[0][1]), fmaxf(st[0][2], st[0][3])),
                      fmaxf(fmaxf(st[1][0], st[1][1]), fmaxf(st[1][2], st[1][3]))),
                fmaxf(fmaxf(fmaxf(st[2][0], st[2][1]), fmaxf(st[2][2], st[2][3])),
                      fmaxf(fmaxf(st[3][0], st[3][1]), fmaxf(st[3][2], st[3][3]))));
            pmax = fmaxf(pmax, __shfl_xor(pmax, 16));
            pmax = fmaxf(pmax, __shfl_xor(pmax, 32));

            if (__all(pmax <= m + 8.0f)) {
                float r0 = 0.f;
                #pragma unroll
                for (int nt = 0; nt < 4; ++nt)
                    #pragma unroll
                    for (int rr = 0; rr < 4; ++rr) {
                        const float p = __expf(st[nt][rr] - m);
                        st[nt][rr] = p;
                        r0 += p;
                    }
                r0 += __shfl_xor(r0, 16);
                r0 += __shfl_xor(r0, 32);
                l += r0;
            } else {
                const float mn = fmaxf(m, pmax);
                const float scf = __expf(m - mn);
                m = mn;
                float r0 = 0.f;
                #pragma unroll
                for (int nt = 0; nt < 4; ++nt)
                    #pragma unroll
                    for (int rr = 0; rr < 4; ++rr) {
                        const float p = __expf(st[nt][rr] - mn);
                        st[nt][rr] = p;
                        r0 += p;
                    }
                r0 += __shfl_xor(r0, 16);
                r0 += __shfl_xor(r0, 32);
                l = l * scf + r0;
                float sc4[4];
                #pragma unroll
                for (int rr = 0; rr < 4; ++rr) sc4[rr] = __shfl(scf, g * 4 + rr);
                #pragma unroll
                for (int nt = 0; nt < 4; ++nt)
                    #pragma unroll
                    for (int rr = 0; rr < 4; ++rr)
                        o[nt][rr] *= sc4[rr];
            }

            unsigned short* Pw = Psw[wave];
            #pragma unroll
            for (int nt = 0; nt < 4; ++nt) {
                const unsigned int w0 = cvt_pk_bf16(st[nt][0], st[nt][1]);
                const unsigned int w1 = cvt_pk_bf16(st[nt][2], st[nt][3]);
                const int off = (l16 * 128 + nt * 32 + g * 8) ^ ((l16 & 7) << 4);
                const unsigned long long dw = ((unsigned long long)w1 << 32) | w0;
                *(unsigned long long*)((char*)Pw + off) = dw;
            }

            __builtin_amdgcn_s_setprio(1);
            #pragma unroll
            for (int ks = 0; ks < 2; ++ks) {
                const int offp = (l16 * 128 + g * 16 + ks * 64) ^ ((l16 & 7) << 4);
                s16x8 pf = __builtin_bit_cast(s16x8, *(const u16x8*)((const char*)Pw + offp));
                #pragma unroll
                for (int nt = 0; nt < 4; ++nt) {
                    const int row = nt * 16 + l16;
                    const int off = (row * 128 + g * 16 + ks * 64) ^ ((row & 7) << 4);
                    s16x8 vf = __builtin_bit_cast(s16x8, *(const u16x8*)(Vb + off));
                    o[nt] = __builtin_amdgcn_mfma_f32_16x16x32_bf16(pf, vf, o[nt], 0, 0, 0);
                }
            }
            __builtin_amdgcn_s_setprio(0);
        }

        if (hn) {
            *(u16x8*)((char*)Ksw[cur ^ 1] + soff) = kn;
            *(u16x8*)((char*)Vsw[cur ^ 1] + soff) = vn;
        }
        __syncthreads();
        cur ^= 1;
    }

    #pragma unroll
    for (int rr = 0; rr < 4; ++rr) {
        const float lq = __shfl(l, g * 4 + rr);
        const float inv = 1.0f / lq;
        const int q_g = qrow0 + g * 4 + rr;
        #pragma unroll
        for (int nt = 0; nt < 4; ++nt) {
            const int d = nt * 16 + l16;
            Ctx[((size_t)b * 2048 + q_g) * 1024 + h * 64 + d] = f2bf(o[nt][rr] * inv);
        }
    }
}

// =====================================================================
extern "C" void kernel_launch(void* const* d_in, const int* in_sizes, int n_in,
                              void* d_out, int out_size, void* d_ws, size_t ws_size,
                              hipStream_t stream)
{
    const float* q  = (const float*)d_in[0];
    const float* k  = (const float*)d_in[1];
    const float* v  = (const float*)d_in[2];
    const float* Wq = (const float*)d_in[4];
    const float* Wk = (const float*)d_in[5];
    const float* Wv = (const float*)d_in[6];
    const float* Wo = (const float*)d_in[7];

    const size_t NE = (size_t)4 * 16 * 2048 * 64;     // 8,388,608 elems / tensor
    unsigned short* Qh  = (unsigned short*)d_ws;
    unsigned short* Kh  = Qh + NE;
    unsigned short* Vt  = Kh + NE;
    unsigned short* Ctx = Vt + NE;                    // 64 MB total (ws >= 67.1 MB proven)
    float* outp = (float*)d_out;

    // fused QKV projections, fp32 inputs converted in-kernel
    gemmF<0><<<dim3(768), dim3(512), 0, stream>>>(
        q, k, v, nullptr, Wq, Wk, Wv, Qh, Kh, Vt, nullptr);
    attn_kernel<<<dim3(1024), dim3(512), 0, stream>>>(Qh, Kh, Vt, Ctx);
    // output projection: Ctx bf16 x Wo fp32 -> fp32 out
    gemmF<1><<<dim3(256), dim3(512), 0, stream>>>(
        nullptr, nullptr, nullptr, Ctx, Wo, nullptr, nullptr,
        nullptr, nullptr, nullptr, outp);
}

// Round 14
// 174.420 us; speedup vs baseline: 1.1194x; 1.0266x over previous
//
#include <hip/hip_runtime.h>

// ---------- types ----------
typedef __attribute__((ext_vector_type(4))) float  f32x4;
typedef __attribute__((ext_vector_type(8))) short  s16x8;   // 8 bf16 (4 VGPRs)
typedef __attribute__((ext_vector_type(8))) unsigned short u16x8;
typedef __attribute__((ext_vector_type(4))) unsigned short u16x4;
typedef __attribute__((ext_vector_type(4))) unsigned int   u32x4;

static __device__ __forceinline__ unsigned short f2bf(float f) {
    unsigned int u = __builtin_bit_cast(unsigned int, f);
    u += 0x7fffu + ((u >> 16) & 1u);      // round-to-nearest-even
    return (unsigned short)(u >> 16);
}

static __device__ __forceinline__ unsigned int cvt_pk_bf16(float lo, float hi) {
    unsigned int r;
    asm("v_cvt_pk_bf16_f32 %0, %1, %2" : "=v"(r) : "v"(lo), "v"(hi));
    return r;
}

static __device__ __forceinline__ void gload16(const void* g, void* l) {
    __builtin_amdgcn_global_load_lds(
        (const __attribute__((address_space(1))) void*)g,
        (__attribute__((address_space(3))) void*)l, 16, 0, 0);
}

// =====================================================================
// QKV GEMM: 256x128 tile, BK=64, 8 waves (4M x 2N), dbuf swizzled LDS
// (96 KB), fp32->bf16 in-kernel staging with 2-DEEP register pipeline:
//   iter t: {issue loads(t+2) -> regset[t%2]}           (window = full iter)
//           {ds_read LDS[t%2] + 32 MFMA}
//           {cvt+swizzled-write regset[(t+1)%2] -> LDS[(t+1)%2]}
//           {__syncthreads}
// Compiler emits COUNTED vmcnt before the write (newer loads in flight).
// grid 768, XCD-swizzled. seg0->Qh*0.125 ; seg1->Kh ; seg2->Vt[B,H,64,L].
// =====================================================================
__global__ __launch_bounds__(512)
void gemmQKV(const float* __restrict__ A0f, const float* __restrict__ A1f,
             const float* __restrict__ A2f,
             const float* __restrict__ B0f, const float* __restrict__ B1f,
             const float* __restrict__ B2f,
             unsigned short* __restrict__ O0, unsigned short* __restrict__ O1,
             unsigned short* __restrict__ O2)
{
    __shared__ unsigned short Asw[2][256 * 64];   // 64 KB
    __shared__ unsigned short Bsw[2][128 * 64];   // 32 KB

    const int tid  = threadIdx.x;
    const int lane = tid & 63;
    const int wave = tid >> 6;
    const int wr   = wave >> 1, wc = wave & 1;    // 4M x 2N waves, 64x64 each
    const int g    = lane >> 4, l16 = lane & 15;

    const int wg   = (blockIdx.x & 7) * 96 + (blockIdx.x >> 3);  // bijective XCD swizzle
    const int bx   = wg & 7;
    const int byt  = wg >> 3;
    const int seg  = byt >> 5;
    const int byl  = byt & 31;

    const float* Af = seg == 0 ? A0f : seg == 1 ? A1f : A2f;
    const float* Arowf = Af + (size_t)(byl * 256) * 1024;
    const float* Browf = (seg == 0 ? B0f : seg == 1 ? B1f : B2f)
                       + (size_t)(bx * 128) * 1024;

    f32x4 acc[4][4] = {};

    // two static staging reg sets (rule 20: all indexing compile-time)
    f32x4 a0lo[4], a0hi[4], a1lo[4], a1hi[4];
    f32x4 b0lo[2], b0hi[2], b1lo[2], b1hi[2];

    auto loadA = [&](f32x4* lo, f32x4* hi, int kt2) {
        #pragma unroll
        for (int j = 0; j < 4; ++j) {
            const float* p = Arowf + (size_t)((j * 512 + tid) >> 3) * 1024
                           + kt2 * 64 + (tid & 7) * 8;
            lo[j] = *(const f32x4*)p;
            hi[j] = *(const f32x4*)(p + 4);
        }
    };
    auto loadB = [&](f32x4* lo, f32x4* hi, int kt2) {
        #pragma unroll
        for (int j = 0; j < 2; ++j) {
            const float* p = Browf + (size_t)((j * 512 + tid) >> 3) * 1024
                           + kt2 * 64 + (tid & 7) * 8;
            lo[j] = *(const f32x4*)p;
            hi[j] = *(const f32x4*)(p + 4);
        }
    };
    auto writeA = [&](const f32x4* lo, const f32x4* hi, int buf) {
        #pragma unroll
        for (int j = 0; j < 4; ++j) {
            const int r = (j * 512 + tid) >> 3, c = tid & 7;
            u32x4 w;
            w[0] = cvt_pk_bf16(lo[j][0], lo[j][1]);
            w[1] = cvt_pk_bf16(lo[j][2], lo[j][3]);
            w[2] = cvt_pk_bf16(hi[j][0], hi[j][1]);
            w[3] = cvt_pk_bf16(hi[j][2], hi[j][3]);
            *(u32x4*)((char*)Asw[buf] + ((r * 128 + c * 16) ^ ((r & 7) << 4))) = w;
        }
    };
    auto writeB = [&](const f32x4* lo, const f32x4* hi, int buf) {
        #pragma unroll
        for (int j = 0; j < 2; ++j) {
            const int r = (j * 512 + tid) >> 3, c = tid & 7;
            u32x4 w;
            w[0] = cvt_pk_bf16(lo[j][0], lo[j][1]);
            w[1] = cvt_pk_bf16(lo[j][2], lo[j][3]);
            w[2] = cvt_pk_bf16(hi[j][0], hi[j][1]);
            w[3] = cvt_pk_bf16(hi[j][2], hi[j][3]);
            *(u32x4*)((char*)Bsw[buf] + ((r * 128 + c * 16) ^ ((r & 7) << 4))) = w;
        }
    };
    auto compute = [&](const char* Ab, const char* Bb) {
        #pragma unroll
        for (int ks = 0; ks < 2; ++ks) {
            s16x8 af[4], bf[4];
            #pragma unroll
            for (int mi = 0; mi < 4; ++mi) {
                const int row = wr * 64 + mi * 16 + l16;
                const int off = (row * 128 + g * 16 + ks * 64) ^ ((row & 7) << 4);
                af[mi] = __builtin_bit_cast(s16x8, *(const u16x8*)(Ab + off));
            }
            #pragma unroll
            for (int ni = 0; ni < 4; ++ni) {
                const int row = wc * 64 + ni * 16 + l16;
                const int off = (row * 128 + g * 16 + ks * 64) ^ ((row & 7) << 4);
                bf[ni] = __builtin_bit_cast(s16x8, *(const u16x8*)(Bb + off));
            }
            __builtin_amdgcn_s_setprio(1);
            #pragma unroll
            for (int mi = 0; mi < 4; ++mi)
                #pragma unroll
                for (int ni = 0; ni < 4; ++ni)
                    acc[mi][ni] = __builtin_amdgcn_mfma_f32_16x16x32_bf16(
                        af[mi], bf[ni], acc[mi][ni], 0, 0, 0);
            __builtin_amdgcn_s_setprio(0);
        }
    };

    // ---- prologue: tile0 -> LDS0 (via set0); tile1 -> set1 ----
    loadA(a0lo, a0hi, 0); loadB(b0lo, b0hi, 0);
    writeA(a0lo, a0hi, 0); writeB(b0lo, b0hi, 0);
    loadA(a1lo, a1hi, 1); loadB(b1lo, b1hi, 1);
    __syncthreads();

    for (int tt = 0; tt < 8; ++tt) {
        // ---- even iter t = 2tt: loads(t+2)->set0; compute LDS0; write set1 ----
        if (tt < 7) { loadA(a0lo, a0hi, 2 * tt + 2); loadB(b0lo, b0hi, 2 * tt + 2); }
        compute((const char*)Asw[0], (const char*)Bsw[0]);
        writeA(a1lo, a1hi, 1); writeB(b1lo, b1hi, 1);   // tile 2tt+1 (always valid)
        __syncthreads();
        // ---- odd iter t = 2tt+1: loads(t+2)->set1; compute LDS1; write set0 ----
        if (tt < 7) { loadA(a1lo, a1hi, 2 * tt + 3); loadB(b1lo, b1hi, 2 * tt + 3); }
        compute((const char*)Asw[1], (const char*)Bsw[1]);
        if (tt < 7) { writeA(a0lo, a0hi, 0); writeB(b0lo, b0hi, 0); }  // tile 2tt+2
        __syncthreads();
    }

    // ---- epilogue ----
    #pragma unroll
    for (int mi = 0; mi < 4; ++mi) {
        #pragma unroll
        for (int ni = 0; ni < 4; ++ni) {
            const int gr0 = byl * 256 + wr * 64 + mi * 16 + g * 4;      // M base
            const int gc  = bx * 128 + wc * 64 + ni * 16 + l16;         // N
            if (seg == 2) {
                // Vt [B,H,64,L]: pack 4 consecutive ll into one 8B store
                const int b = gr0 >> 11, ll = gr0 & 2047;
                const int h = gc >> 6,  dh = gc & 63;
                u16x4 pk;
                #pragma unroll
                for (int rr = 0; rr < 4; ++rr) pk[rr] = f2bf(acc[mi][ni][rr]);
                *(u16x4*)(O2 + (size_t)((b * 16 + h) * 64 + dh) * 2048 + ll) = pk;
            } else {
                #pragma unroll
                for (int rr = 0; rr < 4; ++rr) {
                    const int gr = gr0 + rr;
                    float v = acc[mi][ni][rr];
                    const int b = gr >> 11, ll = gr & 2047;
                    const int h = gc >> 6,  dh = gc & 63;
                    if (seg == 0) {
                        v *= 0.125f;
                        O0[(size_t)((b * 16 + h) * 2048 + ll) * 64 + dh] = f2bf(v);
                    } else {
                        O1[(size_t)((b * 16 + h) * 2048 + ll) * 64 + dh] = f2bf(v);
                    }
                }
            }
        }
    }
}

// =====================================================================
// Out-proj GEMM (R13 EPI1 verbatim): A = Ctx bf16 via gload_lds (dbuf,
// pre-swizzled source), B = Wo fp32 reg-staged depth-1. grid 256.
// =====================================================================
__global__ __launch_bounds__(512)
void gemmO(const unsigned short* __restrict__ Ab16,
           const float* __restrict__ Bf, float* __restrict__ Of)
{
    __shared__ unsigned short Asw[2][256 * 64];   // 64 KB
    __shared__ unsigned short Bsw[2][128 * 64];   // 32 KB

    const int tid  = threadIdx.x;
    const int lane = tid & 63;
    const int wave = tid >> 6;
    const int wr   = wave >> 1, wc = wave & 1;
    const int g    = lane >> 4, l16 = lane & 15;

    const int wg   = (blockIdx.x & 7) * 32 + (blockIdx.x >> 3);
    const int bx   = wg & 7;
    const int byl  = wg >> 3;

    const unsigned short* Arowb = Ab16 + (size_t)(byl * 256) * 1024;
    const float* Browf = Bf + (size_t)(bx * 128) * 1024;

    f32x4 acc[4][4] = {};
    f32x4 blo[2], bhi[2];

    auto loadBf = [&](int kt2) {
        #pragma unroll
        for (int j = 0; j < 2; ++j) {
            const float* p = Browf + (size_t)((j * 512 + tid) >> 3) * 1024
                           + kt2 * 64 + (tid & 7) * 8;
            blo[j] = *(const f32x4*)p;
            bhi[j] = *(const f32x4*)(p + 4);
        }
    };
    auto writeB = [&](int buf) {
        #pragma unroll
        for (int j = 0; j < 2; ++j) {
            const int r = (j * 512 + tid) >> 3, c = tid & 7;
            u32x4 w;
            w[0] = cvt_pk_bf16(blo[j][0], blo[j][1]);
            w[1] = cvt_pk_bf16(blo[j][2], blo[j][3]);
            w[2] = cvt_pk_bf16(bhi[j][0], bhi[j][1]);
            w[3] = cvt_pk_bf16(bhi[j][2], bhi[j][3]);
            *(u32x4*)((char*)Bsw[buf] + ((r * 128 + c * 16) ^ ((r & 7) << 4))) = w;
        }
    };
    auto gloadA = [&](int buf, int kt2) {
        #pragma unroll
        for (int j = 0; j < 4; ++j) {
            const int r  = (j * 512 + tid) >> 3;
            const int cl = (tid & 7) ^ (r & 7);
            gload16(Arowb + (size_t)r * 1024 + kt2 * 64 + cl * 8,
                    (char*)Asw[buf] + j * 8192 + wave * 1024);
        }
    };

    gloadA(0, 0);
    loadBf(0);
    writeB(0);
    __syncthreads();

    int cur = 0;
    for (int t = 0; t < 16; ++t) {
        const bool hn = (t + 1 < 16);
        if (hn) { gloadA(cur ^ 1, t + 1); loadBf(t + 1); }

        const char* Ab = (const char*)Asw[cur];
        const char* Bb = (const char*)Bsw[cur];
        #pragma unroll
        for (int ks = 0; ks < 2; ++ks) {
            s16x8 af[4], bf[4];
            #pragma unroll
            for (int mi = 0; mi < 4; ++mi) {
                const int row = wr * 64 + mi * 16 + l16;
                const int off = (row * 128 + g * 16 + ks * 64) ^ ((row & 7) << 4);
                af[mi] = __builtin_bit_cast(s16x8, *(const u16x8*)(Ab + off));
            }
            #pragma unroll
            for (int ni = 0; ni < 4; ++ni) {
                const int row = wc * 64 + ni * 16 + l16;
                const int off = (row * 128 + g * 16 + ks * 64) ^ ((row & 7) << 4);
                bf[ni] = __builtin_bit_cast(s16x8, *(const u16x8*)(Bb + off));
            }
            __builtin_amdgcn_s_setprio(1);
            #pragma unroll
            for (int mi = 0; mi < 4; ++mi)
                #pragma unroll
                for (int ni = 0; ni < 4; ++ni)
                    acc[mi][ni] = __builtin_amdgcn_mfma_f32_16x16x32_bf16(
                        af[mi], bf[ni], acc[mi][ni], 0, 0, 0);
            __builtin_amdgcn_s_setprio(0);
        }

        if (hn) writeB(cur ^ 1);
        __syncthreads();
        cur ^= 1;
    }

    #pragma unroll
    for (int mi = 0; mi < 4; ++mi) {
        #pragma unroll
        for (int ni = 0; ni < 4; ++ni) {
            const int gr0 = byl * 256 + wr * 64 + mi * 16 + g * 4;
            const int gc  = bx * 128 + wc * 64 + ni * 16 + l16;
            #pragma unroll
            for (int rr = 0; rr < 4; ++rr)
                Of[(size_t)(gr0 + rr) * 1024 + gc] = acc[mi][ni][rr];
        }
    }
}

// =====================================================================
// Flash-style causal attention (R13 verbatim).
// =====================================================================
__global__ __launch_bounds__(512)
void attn_kernel(const unsigned short* __restrict__ Qh,
                 const unsigned short* __restrict__ Kh,
                 const unsigned short* __restrict__ Vt,
                 unsigned short* __restrict__ Ctx)
{
    __shared__ unsigned short Ksw[2][64 * 64];
    __shared__ unsigned short Vsw[2][64 * 64];
    __shared__ unsigned short Psw[8][16 * 64];

    const int tid  = threadIdx.x;
    const int lane = tid & 63;
    const int wave = tid >> 6;
    const int g    = lane >> 4, l16 = lane & 15;
    const int qb   = 15 - (int)(blockIdx.x >> 6);
    const int bh   = blockIdx.x & 63;
    const int b    = bh >> 4, h = bh & 15;
    const int qrow0 = qb * 128 + wave * 16;
    const int ntile = 2 * qb + 2;

    const int sr = tid >> 3, sc = tid & 7;
    const int soff = (sr * 128 + sc * 16) ^ ((sr & 7) << 4);
    const unsigned short* kbase = Kh + ((size_t)bh * 2048 + sr) * 64 + sc * 8;
    const unsigned short* vbase = Vt + ((size_t)bh * 64 + sr) * 2048 + sc * 8;

    s16x8 qf[2];
    {
        const unsigned short* qp = Qh + ((size_t)bh * 2048 + qrow0 + l16) * 64 + g * 8;
        qf[0] = __builtin_bit_cast(s16x8, *(const u16x8*)qp);
        qf[1] = __builtin_bit_cast(s16x8, *(const u16x8*)(qp + 32));
    }

    f32x4 o[4] = {};
    float m = -3.0e38f, l = 0.f;   // per-lane row state: q = l16

    *(u16x8*)((char*)Ksw[0] + soff) = *(const u16x8*)kbase;
    *(u16x8*)((char*)Vsw[0] + soff) = *(const u16x8*)vbase;
    __syncthreads();

    int cur = 0;
    for (int t = 0; t < ntile; ++t) {
        const int kv0 = t * 64;

        u16x8 kn, vn;
        const bool hn = (t + 1 < ntile);
        if (hn) {
            kn = *(const u16x8*)(kbase + (size_t)(kv0 + 64) * 64);
            vn = *(const u16x8*)(vbase + (kv0 + 64));
        }

        if (kv0 <= qrow0 + 15) {
            const char* Kb = (const char*)Ksw[cur];
            const char* Vb = (const char*)Vsw[cur];

            f32x4 st[4] = {};
            __builtin_amdgcn_s_setprio(1);
            #pragma unroll
            for (int nt = 0; nt < 4; ++nt) {
                #pragma unroll
                for (int ks = 0; ks < 2; ++ks) {
                    const int row = nt * 16 + l16;
                    const int off = (row * 128 + g * 16 + ks * 64) ^ ((row & 7) << 4);
                    s16x8 kf = __builtin_bit_cast(s16x8, *(const u16x8*)(Kb + off));
                    st[nt] = __builtin_amdgcn_mfma_f32_16x16x32_bf16(kf, qf[ks], st[nt], 0, 0, 0);
                }
            }
            __builtin_amdgcn_s_setprio(0);

            if (kv0 + 63 > qrow0) {
                const int q_g = qrow0 + l16;
                #pragma unroll
                for (int nt = 0; nt < 4; ++nt)
                    #pragma unroll
                    for (int rr = 0; rr < 4; ++rr) {
                        const int kv_g = kv0 + nt * 16 + g * 4 + rr;
                        if (kv_g > q_g) st[nt][rr] = -3.0e38f;
                    }
            }

            float pmax = fmaxf(
                fmaxf(fmaxf(fmaxf(st[0][0], st[0][1]), fmaxf(st[0][2], st[0][3])),
                      fmaxf(fmaxf(st[1][0], st[1][1]), fmaxf(st[1][2], st[1][3]))),
                fmaxf(fmaxf(fmaxf(st[2][0], st[2][1]), fmaxf(st[2][2], st[2][3])),
                      fmaxf(fmaxf(st[3][0], st[3][1]), fmaxf(st[3][2], st[3][3]))));
            pmax = fmaxf(pmax, __shfl_xor(pmax, 16));
            pmax = fmaxf(pmax, __shfl_xor(pmax, 32));

            if (__all(pmax <= m + 8.0f)) {
                float r0 = 0.f;
                #pragma unroll
                for (int nt = 0; nt < 4; ++nt)
                    #pragma unroll
                    for (int rr = 0; rr < 4; ++rr) {
                        const float p = __expf(st[nt][rr] - m);
                        st[nt][rr] = p;
                        r0 += p;
                    }
                r0 += __shfl_xor(r0, 16);
                r0 += __shfl_xor(r0, 32);
                l += r0;
            } else {
                const float mn = fmaxf(m, pmax);
                const float scf = __expf(m - mn);
                m = mn;
                float r0 = 0.f;
                #pragma unroll
                for (int nt = 0; nt < 4; ++nt)
                    #pragma unroll
                    for (int rr = 0; rr < 4; ++rr) {
                        const float p = __expf(st[nt][rr] - mn);
                        st[nt][rr] = p;
                        r0 += p;
                    }
                r0 += __shfl_xor(r0, 16);
                r0 += __shfl_xor(r0, 32);
                l = l * scf + r0;
                float sc4[4];
                #pragma unroll
                for (int rr = 0; rr < 4; ++rr) sc4[rr] = __shfl(scf, g * 4 + rr);
                #pragma unroll
                for (int nt = 0; nt < 4; ++nt)
                    #pragma unroll
                    for (int rr = 0; rr < 4; ++rr)
                        o[nt][rr] *= sc4[rr];
            }

            unsigned short* Pw = Psw[wave];
            #pragma unroll
            for (int nt = 0; nt < 4; ++nt) {
                const unsigned int w0 = cvt_pk_bf16(st[nt][0], st[nt][1]);
                const unsigned int w1 = cvt_pk_bf16(st[nt][2], st[nt][3]);
                const int off = (l16 * 128 + nt * 32 + g * 8) ^ ((l16 & 7) << 4);
                const unsigned long long dw = ((unsigned long long)w1 << 32) | w0;
                *(unsigned long long*)((char*)Pw + off) = dw;
            }

            __builtin_amdgcn_s_setprio(1);
            #pragma unroll
            for (int ks = 0; ks < 2; ++ks) {
                const int offp = (l16 * 128 + g * 16 + ks * 64) ^ ((l16 & 7) << 4);
                s16x8 pf = __builtin_bit_cast(s16x8, *(const u16x8*)((const char*)Pw + offp));
                #pragma unroll
                for (int nt = 0; nt < 4; ++nt) {
                    const int row = nt * 16 + l16;
                    const int off = (row * 128 + g * 16 + ks * 64) ^ ((row & 7) << 4);
                    s16x8 vf = __builtin_bit_cast(s16x8, *(const u16x8*)(Vb + off));
                    o[nt] = __builtin_amdgcn_mfma_f32_16x16x32_bf16(pf, vf, o[nt], 0, 0, 0);
                }
            }
            __builtin_amdgcn_s_setprio(0);
        }

        if (hn) {
            *(u16x8*)((char*)Ksw[cur ^ 1] + soff) = kn;
            *(u16x8*)((char*)Vsw[cur ^ 1] + soff) = vn;
        }
        __syncthreads();
        cur ^= 1;
    }

    #pragma unroll
    for (int rr = 0; rr < 4; ++rr) {
        const float lq = __shfl(l, g * 4 + rr);
        const float inv = 1.0f / lq;
        const int q_g = qrow0 + g * 4 + rr;
        #pragma unroll
        for (int nt = 0; nt < 4; ++nt) {
            const int d = nt * 16 + l16;
            Ctx[((size_t)b * 2048 + q_g) * 1024 + h * 64 + d] = f2bf(o[nt][rr] * inv);
        }
    }
}

// =====================================================================
extern "C" void kernel_launch(void* const* d_in, const int* in_sizes, int n_in,
                              void* d_out, int out_size, void* d_ws, size_t ws_size,
                              hipStream_t stream)
{
    const float* q  = (const float*)d_in[0];
    const float* k  = (const float*)d_in[1];
    const float* v  = (const float*)d_in[2];
    const float* Wq = (const float*)d_in[4];
    const float* Wk = (const float*)d_in[5];
    const float* Wv = (const float*)d_in[6];
    const float* Wo = (const float*)d_in[7];

    const size_t NE = (size_t)4 * 16 * 2048 * 64;     // 8,388,608 elems / tensor
    unsigned short* Qh  = (unsigned short*)d_ws;
    unsigned short* Kh  = Qh + NE;
    unsigned short* Vt  = Kh + NE;
    unsigned short* Ctx = Vt + NE;                    // 64 MB total
    float* outp = (float*)d_out;

    gemmQKV<<<dim3(768), dim3(512), 0, stream>>>(
        q, k, v, Wq, Wk, Wv, Qh, Kh, Vt);
    attn_kernel<<<dim3(1024), dim3(512), 0, stream>>>(Qh, Kh, Vt, Ctx);
    gemmO<<<dim3(256), dim3(512), 0, stream>>>(Ctx, Wo, outp);
}

// Round 15
// 170.778 us; speedup vs baseline: 1.1432x; 1.0213x over previous
//
#include <hip/hip_runtime.h>

// ---------- types ----------
typedef __attribute__((ext_vector_type(4))) float  f32x4;
typedef __attribute__((ext_vector_type(8))) short  s16x8;   // 8 bf16 (4 VGPRs)
typedef __attribute__((ext_vector_type(8))) unsigned short u16x8;
typedef __attribute__((ext_vector_type(4))) unsigned short u16x4;
typedef __attribute__((ext_vector_type(4))) unsigned int   u32x4;

static __device__ __forceinline__ unsigned short f2bf(float f) {
    unsigned int u = __builtin_bit_cast(unsigned int, f);
    u += 0x7fffu + ((u >> 16) & 1u);      // round-to-nearest-even
    return (unsigned short)(u >> 16);
}

static __device__ __forceinline__ unsigned int cvt_pk_bf16(float lo, float hi) {
    unsigned int r;
    asm("v_cvt_pk_bf16_f32 %0, %1, %2" : "=v"(r) : "v"(lo), "v"(hi));
    return r;
}

static __device__ __forceinline__ void gload16(const void* g, void* l) {
    __builtin_amdgcn_global_load_lds(
        (const __attribute__((address_space(1))) void*)g,
        (__attribute__((address_space(3))) void*)l, 16, 0, 0);
}

// =====================================================================
// QKV GEMM (R14 verbatim — measured best, 130 us):
// 256x128 tile, BK=64, 8 waves (4M x 2N), dbuf swizzled LDS (96 KB),
// fp32->bf16 staging with 2-DEEP register pipeline:
//   iter t: {issue loads(t+2) -> regset[t%2]}
//           {ds_read LDS[t%2] + 32 MFMA}
//           {cvt+swizzled-write regset[(t+1)%2] -> LDS[(t+1)%2]}
//           {__syncthreads}
// grid 768, XCD-swizzled. seg0->Qh*0.125 ; seg1->Kh ; seg2->Vt[B,H,64,L].
// =====================================================================
__global__ __launch_bounds__(512)
void gemmQKV(const float* __restrict__ A0f, const float* __restrict__ A1f,
             const float* __restrict__ A2f,
             const float* __restrict__ B0f, const float* __restrict__ B1f,
             const float* __restrict__ B2f,
             unsigned short* __restrict__ O0, unsigned short* __restrict__ O1,
             unsigned short* __restrict__ O2)
{
    __shared__ unsigned short Asw[2][256 * 64];   // 64 KB
    __shared__ unsigned short Bsw[2][128 * 64];   // 32 KB

    const int tid  = threadIdx.x;
    const int lane = tid & 63;
    const int wave = tid >> 6;
    const int wr   = wave >> 1, wc = wave & 1;    // 4M x 2N waves, 64x64 each
    const int g    = lane >> 4, l16 = lane & 15;

    const int wg   = (blockIdx.x & 7) * 96 + (blockIdx.x >> 3);  // bijective XCD swizzle
    const int bx   = wg & 7;
    const int byt  = wg >> 3;
    const int seg  = byt >> 5;
    const int byl  = byt & 31;

    const float* Af = seg == 0 ? A0f : seg == 1 ? A1f : A2f;
    const float* Arowf = Af + (size_t)(byl * 256) * 1024;
    const float* Browf = (seg == 0 ? B0f : seg == 1 ? B1f : B2f)
                       + (size_t)(bx * 128) * 1024;

    f32x4 acc[4][4] = {};

    // two static staging reg sets (rule 20: all indexing compile-time)
    f32x4 a0lo[4], a0hi[4], a1lo[4], a1hi[4];
    f32x4 b0lo[2], b0hi[2], b1lo[2], b1hi[2];

    auto loadA = [&](f32x4* lo, f32x4* hi, int kt2) {
        #pragma unroll
        for (int j = 0; j < 4; ++j) {
            const float* p = Arowf + (size_t)((j * 512 + tid) >> 3) * 1024
                           + kt2 * 64 + (tid & 7) * 8;
            lo[j] = *(const f32x4*)p;
            hi[j] = *(const f32x4*)(p + 4);
        }
    };
    auto loadB = [&](f32x4* lo, f32x4* hi, int kt2) {
        #pragma unroll
        for (int j = 0; j < 2; ++j) {
            const float* p = Browf + (size_t)((j * 512 + tid) >> 3) * 1024
                           + kt2 * 64 + (tid & 7) * 8;
            lo[j] = *(const f32x4*)p;
            hi[j] = *(const f32x4*)(p + 4);
        }
    };
    auto writeA = [&](const f32x4* lo, const f32x4* hi, int buf) {
        #pragma unroll
        for (int j = 0; j < 4; ++j) {
            const int r = (j * 512 + tid) >> 3, c = tid & 7;
            u32x4 w;
            w[0] = cvt_pk_bf16(lo[j][0], lo[j][1]);
            w[1] = cvt_pk_bf16(lo[j][2], lo[j][3]);
            w[2] = cvt_pk_bf16(hi[j][0], hi[j][1]);
            w[3] = cvt_pk_bf16(hi[j][2], hi[j][3]);
            *(u32x4*)((char*)Asw[buf] + ((r * 128 + c * 16) ^ ((r & 7) << 4))) = w;
        }
    };
    auto writeB = [&](const f32x4* lo, const f32x4* hi, int buf) {
        #pragma unroll
        for (int j = 0; j < 2; ++j) {
            const int r = (j * 512 + tid) >> 3, c = tid & 7;
            u32x4 w;
            w[0] = cvt_pk_bf16(lo[j][0], lo[j][1]);
            w[1] = cvt_pk_bf16(lo[j][2], lo[j][3]);
            w[2] = cvt_pk_bf16(hi[j][0], hi[j][1]);
            w[3] = cvt_pk_bf16(hi[j][2], hi[j][3]);
            *(u32x4*)((char*)Bsw[buf] + ((r * 128 + c * 16) ^ ((r & 7) << 4))) = w;
        }
    };
    auto compute = [&](const char* Ab, const char* Bb) {
        #pragma unroll
        for (int ks = 0; ks < 2; ++ks) {
            s16x8 af[4], bf[4];
            #pragma unroll
            for (int mi = 0; mi < 4; ++mi) {
                const int row = wr * 64 + mi * 16 + l16;
                const int off = (row * 128 + g * 16 + ks * 64) ^ ((row & 7) << 4);
                af[mi] = __builtin_bit_cast(s16x8, *(const u16x8*)(Ab + off));
            }
            #pragma unroll
            for (int ni = 0; ni < 4; ++ni) {
                const int row = wc * 64 + ni * 16 + l16;
                const int off = (row * 128 + g * 16 + ks * 64) ^ ((row & 7) << 4);
                bf[ni] = __builtin_bit_cast(s16x8, *(const u16x8*)(Bb + off));
            }
            __builtin_amdgcn_s_setprio(1);
            #pragma unroll
            for (int mi = 0; mi < 4; ++mi)
                #pragma unroll
                for (int ni = 0; ni < 4; ++ni)
                    acc[mi][ni] = __builtin_amdgcn_mfma_f32_16x16x32_bf16(
                        af[mi], bf[ni], acc[mi][ni], 0, 0, 0);
            __builtin_amdgcn_s_setprio(0);
        }
    };

    // ---- prologue: tile0 -> LDS0 (via set0); tile1 -> set1 ----
    loadA(a0lo, a0hi, 0); loadB(b0lo, b0hi, 0);
    writeA(a0lo, a0hi, 0); writeB(b0lo, b0hi, 0);
    loadA(a1lo, a1hi, 1); loadB(b1lo, b1hi, 1);
    __syncthreads();

    for (int tt = 0; tt < 8; ++tt) {
        // ---- even iter t = 2tt ----
        if (tt < 7) { loadA(a0lo, a0hi, 2 * tt + 2); loadB(b0lo, b0hi, 2 * tt + 2); }
        compute((const char*)Asw[0], (const char*)Bsw[0]);
        writeA(a1lo, a1hi, 1); writeB(b1lo, b1hi, 1);
        __syncthreads();
        // ---- odd iter t = 2tt+1 ----
        if (tt < 7) { loadA(a1lo, a1hi, 2 * tt + 3); loadB(b1lo, b1hi, 2 * tt + 3); }
        compute((const char*)Asw[1], (const char*)Bsw[1]);
        if (tt < 7) { writeA(a0lo, a0hi, 0); writeB(b0lo, b0hi, 0); }
        __syncthreads();
    }

    // ---- epilogue ----
    #pragma unroll
    for (int mi = 0; mi < 4; ++mi) {
        #pragma unroll
        for (int ni = 0; ni < 4; ++ni) {
            const int gr0 = byl * 256 + wr * 64 + mi * 16 + g * 4;      // M base
            const int gc  = bx * 128 + wc * 64 + ni * 16 + l16;         // N
            if (seg == 2) {
                const int b = gr0 >> 11, ll = gr0 & 2047;
                const int h = gc >> 6,  dh = gc & 63;
                u16x4 pk;
                #pragma unroll
                for (int rr = 0; rr < 4; ++rr) pk[rr] = f2bf(acc[mi][ni][rr]);
                *(u16x4*)(O2 + (size_t)((b * 16 + h) * 64 + dh) * 2048 + ll) = pk;
            } else {
                #pragma unroll
                for (int rr = 0; rr < 4; ++rr) {
                    const int gr = gr0 + rr;
                    float v = acc[mi][ni][rr];
                    const int b = gr >> 11, ll = gr & 2047;
                    const int h = gc >> 6,  dh = gc & 63;
                    if (seg == 0) {
                        v *= 0.125f;
                        O0[(size_t)((b * 16 + h) * 2048 + ll) * 64 + dh] = f2bf(v);
                    } else {
                        O1[(size_t)((b * 16 + h) * 2048 + ll) * 64 + dh] = f2bf(v);
                    }
                }
            }
        }
    }
}

// =====================================================================
// Out-proj GEMM: A = Ctx bf16 via gload_lds (dbuf, pre-swizzled source,
// issue t+1 at t), B = Wo fp32 with 2-DEEP register staging (mirrors
// the QKV win: loads(t+2) at t, written at t+1). grid 256.
// =====================================================================
__global__ __launch_bounds__(512)
void gemmO(const unsigned short* __restrict__ Ab16,
           const float* __restrict__ Bf, float* __restrict__ Of)
{
    __shared__ unsigned short Asw[2][256 * 64];   // 64 KB
    __shared__ unsigned short Bsw[2][128 * 64];   // 32 KB

    const int tid  = threadIdx.x;
    const int lane = tid & 63;
    const int wave = tid >> 6;
    const int wr   = wave >> 1, wc = wave & 1;
    const int g    = lane >> 4, l16 = lane & 15;

    const int wg   = (blockIdx.x & 7) * 32 + (blockIdx.x >> 3);
    const int bx   = wg & 7;
    const int byl  = wg >> 3;

    const unsigned short* Arowb = Ab16 + (size_t)(byl * 256) * 1024;
    const float* Browf = Bf + (size_t)(bx * 128) * 1024;

    f32x4 acc[4][4] = {};
    f32x4 b0lo[2], b0hi[2], b1lo[2], b1hi[2];   // 2-deep B reg sets

    auto loadB = [&](f32x4* lo, f32x4* hi, int kt2) {
        #pragma unroll
        for (int j = 0; j < 2; ++j) {
            const float* p = Browf + (size_t)((j * 512 + tid) >> 3) * 1024
                           + kt2 * 64 + (tid & 7) * 8;
            lo[j] = *(const f32x4*)p;
            hi[j] = *(const f32x4*)(p + 4);
        }
    };
    auto writeB = [&](const f32x4* lo, const f32x4* hi, int buf) {
        #pragma unroll
        for (int j = 0; j < 2; ++j) {
            const int r = (j * 512 + tid) >> 3, c = tid & 7;
            u32x4 w;
            w[0] = cvt_pk_bf16(lo[j][0], lo[j][1]);
            w[1] = cvt_pk_bf16(lo[j][2], lo[j][3]);
            w[2] = cvt_pk_bf16(hi[j][0], hi[j][1]);
            w[3] = cvt_pk_bf16(hi[j][2], hi[j][3]);
            *(u32x4*)((char*)Bsw[buf] + ((r * 128 + c * 16) ^ ((r & 7) << 4))) = w;
        }
    };
    auto gloadA = [&](int buf, int kt2) {
        #pragma unroll
        for (int j = 0; j < 4; ++j) {
            const int r  = (j * 512 + tid) >> 3;
            const int cl = (tid & 7) ^ (r & 7);
            gload16(Arowb + (size_t)r * 1024 + kt2 * 64 + cl * 8,
                    (char*)Asw[buf] + j * 8192 + wave * 1024);
        }
    };
    auto compute = [&](const char* Ab, const char* Bb) {
        #pragma unroll
        for (int ks = 0; ks < 2; ++ks) {
            s16x8 af[4], bf[4];
            #pragma unroll
            for (int mi = 0; mi < 4; ++mi) {
                const int row = wr * 64 + mi * 16 + l16;
                const int off = (row * 128 + g * 16 + ks * 64) ^ ((row & 7) << 4);
                af[mi] = __builtin_bit_cast(s16x8, *(const u16x8*)(Ab + off));
            }
            #pragma unroll
            for (int ni = 0; ni < 4; ++ni) {
                const int row = wc * 64 + ni * 16 + l16;
                const int off = (row * 128 + g * 16 + ks * 64) ^ ((row & 7) << 4);
                bf[ni] = __builtin_bit_cast(s16x8, *(const u16x8*)(Bb + off));
            }
            __builtin_amdgcn_s_setprio(1);
            #pragma unroll
            for (int mi = 0; mi < 4; ++mi)
                #pragma unroll
                for (int ni = 0; ni < 4; ++ni)
                    acc[mi][ni] = __builtin_amdgcn_mfma_f32_16x16x32_bf16(
                        af[mi], bf[ni], acc[mi][ni], 0, 0, 0);
            __builtin_amdgcn_s_setprio(0);
        }
    };

    // ---- prologue: A tile0 -> LDS0 (async); B tile0 -> LDS0, tile1 -> set1 ----
    gloadA(0, 0);
    loadB(b0lo, b0hi, 0);
    writeB(b0lo, b0hi, 0);
    loadB(b1lo, b1hi, 1);
    __syncthreads();

    for (int tt = 0; tt < 8; ++tt) {
        // ---- even iter t = 2tt ----
        {
            const int t = 2 * tt;
            if (t + 1 < 16) gloadA(1, t + 1);
            if (t + 2 < 16) loadB(b0lo, b0hi, t + 2);
            compute((const char*)Asw[0], (const char*)Bsw[0]);
            writeB(b1lo, b1hi, 1);                 // tile t+1 (always valid, t<=14)
            __syncthreads();
        }
        // ---- odd iter t = 2tt+1 ----
        {
            const int t = 2 * tt + 1;
            if (t + 1 < 16) gloadA(0, t + 1);
            if (t + 2 < 16) loadB(b1lo, b1hi, t + 2);
            compute((const char*)Asw[1], (const char*)Bsw[1]);
            if (t + 1 < 16) writeB(b0lo, b0hi, 0); // tile t+1
            __syncthreads();
        }
    }

    #pragma unroll
    for (int mi = 0; mi < 4; ++mi) {
        #pragma unroll
        for (int ni = 0; ni < 4; ++ni) {
            const int gr0 = byl * 256 + wr * 64 + mi * 16 + g * 4;
            const int gc  = bx * 128 + wc * 64 + ni * 16 + l16;
            #pragma unroll
            for (int rr = 0; rr < 4; ++rr)
                Of[(size_t)(gr0 + rr) * 1024 + gc] = acc[mi][ni][rr];
        }
    }
}

// =====================================================================
// Flash-style causal attention (R13/R14 verbatim).
// =====================================================================
__global__ __launch_bounds__(512)
void attn_kernel(const unsigned short* __restrict__ Qh,
                 const unsigned short* __restrict__ Kh,
                 const unsigned short* __restrict__ Vt,
                 unsigned short* __restrict__ Ctx)
{
    __shared__ unsigned short Ksw[2][64 * 64];
    __shared__ unsigned short Vsw[2][64 * 64];
    __shared__ unsigned short Psw[8][16 * 64];

    const int tid  = threadIdx.x;
    const int lane = tid & 63;
    const int wave = tid >> 6;
    const int g    = lane >> 4, l16 = lane & 15;
    const int qb   = 15 - (int)(blockIdx.x >> 6);
    const int bh   = blockIdx.x & 63;
    const int b    = bh >> 4, h = bh & 15;
    const int qrow0 = qb * 128 + wave * 16;
    const int ntile = 2 * qb + 2;

    const int sr = tid >> 3, sc = tid & 7;
    const int soff = (sr * 128 + sc * 16) ^ ((sr & 7) << 4);
    const unsigned short* kbase = Kh + ((size_t)bh * 2048 + sr) * 64 + sc * 8;
    const unsigned short* vbase = Vt + ((size_t)bh * 64 + sr) * 2048 + sc * 8;

    s16x8 qf[2];
    {
        const unsigned short* qp = Qh + ((size_t)bh * 2048 + qrow0 + l16) * 64 + g * 8;
        qf[0] = __builtin_bit_cast(s16x8, *(const u16x8*)qp);
        qf[1] = __builtin_bit_cast(s16x8, *(const u16x8*)(qp + 32));
    }

    f32x4 o[4] = {};
    float m = -3.0e38f, l = 0.f;   // per-lane row state: q = l16

    *(u16x8*)((char*)Ksw[0] + soff) = *(const u16x8*)kbase;
    *(u16x8*)((char*)Vsw[0] + soff) = *(const u16x8*)vbase;
    __syncthreads();

    int cur = 0;
    for (int t = 0; t < ntile; ++t) {
        const int kv0 = t * 64;

        u16x8 kn, vn;
        const bool hn = (t + 1 < ntile);
        if (hn) {
            kn = *(const u16x8*)(kbase + (size_t)(kv0 + 64) * 64);
            vn = *(const u16x8*)(vbase + (kv0 + 64));
        }

        if (kv0 <= qrow0 + 15) {
            const char* Kb = (const char*)Ksw[cur];
            const char* Vb = (const char*)Vsw[cur];

            f32x4 st[4] = {};
            __builtin_amdgcn_s_setprio(1);
            #pragma unroll
            for (int nt = 0; nt < 4; ++nt) {
                #pragma unroll
                for (int ks = 0; ks < 2; ++ks) {
                    const int row = nt * 16 + l16;
                    const int off = (row * 128 + g * 16 + ks * 64) ^ ((row & 7) << 4);
                    s16x8 kf = __builtin_bit_cast(s16x8, *(const u16x8*)(Kb + off));
                    st[nt] = __builtin_amdgcn_mfma_f32_16x16x32_bf16(kf, qf[ks], st[nt], 0, 0, 0);
                }
            }
            __builtin_amdgcn_s_setprio(0);

            if (kv0 + 63 > qrow0) {
                const int q_g = qrow0 + l16;
                #pragma unroll
                for (int nt = 0; nt < 4; ++nt)
                    #pragma unroll
                    for (int rr = 0; rr < 4; ++rr) {
                        const int kv_g = kv0 + nt * 16 + g * 4 + rr;
                        if (kv_g > q_g) st[nt][rr] = -3.0e38f;
                    }
            }

            float pmax = fmaxf(
                fmaxf(fmaxf(fmaxf(st[0][0], st[0][1]), fmaxf(st[0][2], st[0][3])),
                      fmaxf(fmaxf(st[1][0], st[1][1]), fmaxf(st[1][2], st[1][3]))),
                fmaxf(fmaxf(fmaxf(st[2][0], st[2][1]), fmaxf(st[2][2], st[2][3])),
                      fmaxf(fmaxf(st[3][0], st[3][1]), fmaxf(st[3][2], st[3][3]))));
            pmax = fmaxf(pmax, __shfl_xor(pmax, 16));
            pmax = fmaxf(pmax, __shfl_xor(pmax, 32));

            if (__all(pmax <= m + 8.0f)) {
                float r0 = 0.f;
                #pragma unroll
                for (int nt = 0; nt < 4; ++nt)
                    #pragma unroll
                    for (int rr = 0; rr < 4; ++rr) {
                        const float p = __expf(st[nt][rr] - m);
                        st[nt][rr] = p;
                        r0 += p;
                    }
                r0 += __shfl_xor(r0, 16);
                r0 += __shfl_xor(r0, 32);
                l += r0;
            } else {
                const float mn = fmaxf(m, pmax);
                const float scf = __expf(m - mn);
                m = mn;
                float r0 = 0.f;
                #pragma unroll
                for (int nt = 0; nt < 4; ++nt)
                    #pragma unroll
                    for (int rr = 0; rr < 4; ++rr) {
                        const float p = __expf(st[nt][rr] - mn);
                        st[nt][rr] = p;
                        r0 += p;
                    }
                r0 += __shfl_xor(r0, 16);
                r0 += __shfl_xor(r0, 32);
                l = l * scf + r0;
                float sc4[4];
                #pragma unroll
                for (int rr = 0; rr < 4; ++rr) sc4[rr] = __shfl(scf, g * 4 + rr);
                #pragma unroll
                for (int nt = 0; nt < 4; ++nt)
                    #pragma unroll
                    for (int rr = 0; rr < 4; ++rr)
                        o[nt][rr] *= sc4[rr];
            }

            unsigned short* Pw = Psw[wave];
            #pragma unroll
            for (int nt = 0; nt < 4; ++nt) {
                const unsigned int w0 = cvt_pk_bf16(st[nt][0], st[nt][1]);
                const unsigned int w1 = cvt_pk_bf16(st[nt][2], st[nt][3]);
                const int off = (l16 * 128 + nt * 32 + g * 8) ^ ((l16 & 7) << 4);
                const unsigned long long dw = ((unsigned long long)w1 << 32) | w0;
                *(unsigned long long*)((char*)Pw + off) = dw;
            }

            __builtin_amdgcn_s_setprio(1);
            #pragma unroll
            for (int ks = 0; ks < 2; ++ks) {
                const int offp = (l16 * 128 + g * 16 + ks * 64) ^ ((l16 & 7) << 4);
                s16x8 pf = __builtin_bit_cast(s16x8, *(const u16x8*)((const char*)Pw + offp));
                #pragma unroll
                for (int nt = 0; nt < 4; ++nt) {
                    const int row = nt * 16 + l16;
                    const int off = (row * 128 + g * 16 + ks * 64) ^ ((row & 7) << 4);
                    s16x8 vf = __builtin_bit_cast(s16x8, *(const u16x8*)(Vb + off));
                    o[nt] = __builtin_amdgcn_mfma_f32_16x16x32_bf16(pf, vf, o[nt], 0, 0, 0);
                }
            }
            __builtin_amdgcn_s_setprio(0);
        }

        if (hn) {
            *(u16x8*)((char*)Ksw[cur ^ 1] + soff) = kn;
            *(u16x8*)((char*)Vsw[cur ^ 1] + soff) = vn;
        }
        __syncthreads();
        cur ^= 1;
    }

    #pragma unroll
    for (int rr = 0; rr < 4; ++rr) {
        const float lq = __shfl(l, g * 4 + rr);
        const float inv = 1.0f / lq;
        const int q_g = qrow0 + g * 4 + rr;
        #pragma unroll
        for (int nt = 0; nt < 4; ++nt) {
            const int d = nt * 16 + l16;
            Ctx[((size_t)b * 2048 + q_g) * 1024 + h * 64 + d] = f2bf(o[nt][rr] * inv);
        }
    }
}

// =====================================================================
extern "C" void kernel_launch(void* const* d_in, const int* in_sizes, int n_in,
                              void* d_out, int out_size, void* d_ws, size_t ws_size,
                              hipStream_t stream)
{
    const float* q  = (const float*)d_in[0];
    const float* k  = (const float*)d_in[1];
    const float* v  = (const float*)d_in[2];
    const float* Wq = (const float*)d_in[4];
    const float* Wk = (const float*)d_in[5];
    const float* Wv = (const float*)d_in[6];
    const float* Wo = (const float*)d_in[7];

    const size_t NE = (size_t)4 * 16 * 2048 * 64;     // 8,388,608 elems / tensor
    unsigned short* Qh  = (unsigned short*)d_ws;
    unsigned short* Kh  = Qh + NE;
    unsigned short* Vt  = Kh + NE;
    unsigned short* Ctx = Vt + NE;                    // 64 MB total
    float* outp = (float*)d_out;

    gemmQKV<<<dim3(768), dim3(512), 0, stream>>>(
        q, k, v, Wq, Wk, Wv, Qh, Kh, Vt);
    attn_kernel<<<dim3(1024), dim3(512), 0, stream>>>(Qh, Kh, Vt, Ctx);
    gemmO<<<dim3(256), dim3(512), 0, stream>>>(Ctx, Wo, outp);
}